// Round 4
// baseline (291.771 us; speedup 1.0000x reference)
//
#include <hip/hip_runtime.h>
#include <hip/hip_bf16.h>

#define NPD 30000        // atoms per degree bucket
#define NF  128          // feature dim == filter dim
#define MAXDEG 6
#define TM  64           // output tile rows per block
#define LDK 136          // padded LDS leading dim (bf16 elems)

typedef __attribute__((ext_vector_type(8))) short short8;   // 8 x bf16 (4 VGPRs)
typedef __attribute__((ext_vector_type(4))) float floatx4;  // MFMA accumulator

__device__ __forceinline__ unsigned short f2bf(float f) {
    __hip_bfloat16 h = __float2bfloat16(f);
    return __builtin_bit_cast(unsigned short, h);
}

// ---- W transpose + convert: W[a][k][n] fp32 -> Wt[a][n][k] bf16 ----
__global__ void wt_kernel(const float* __restrict__ W,
                          unsigned short* __restrict__ Wt) {
    __shared__ unsigned short t[32][33];
    const int a  = blockIdx.z;
    const int k0 = blockIdx.x * 32, n0 = blockIdx.y * 32;
    const int tx = threadIdx.x & 31, ty = threadIdx.x >> 5;  // 256 thr: 32x8
    const float*    Wp  = W  + (size_t)a * NF * NF;
    unsigned short* Wtp = Wt + (size_t)a * NF * NF;
#pragma unroll
    for (int i = 0; i < 32; i += 8)
        t[ty + i][tx] = f2bf(Wp[(size_t)(k0 + ty + i) * NF + (n0 + tx)]);
    __syncthreads();
#pragma unroll
    for (int i = 0; i < 32; i += 8)
        Wtp[(size_t)(n0 + ty + i) * NF + (k0 + tx)] = t[tx][ty + i];
}

// ---- fully-unrolled neighbor gather: all index loads, then all data loads ----
template <int DEG>
__device__ __forceinline__ void gather_sum(const int* __restrict__ adj,
                                           const float* __restrict__ atoms,
                                           int row_glob, int kc, float* a32) {
    const int* arow = adj + (size_t)row_glob * DEG;
    int idxs[DEG];
#pragma unroll
    for (int j = 0; j < DEG; j++) idxs[j] = arow[j];
#pragma unroll
    for (int i = 0; i < 32; i++) a32[i] = 0.f;
#pragma unroll
    for (int j = 0; j < DEG; j++) {
        const float4* p = (const float4*)(atoms + (size_t)idxs[j] * NF + kc);
#pragma unroll
        for (int q = 0; q < 8; q++) {
            float4 v = p[q];
            a32[q * 4 + 0] += v.x; a32[q * 4 + 1] += v.y;
            a32[q * 4 + 2] += v.z; a32[q * 4 + 3] += v.w;
        }
    }
}

// ---- fused graph conv: one 64x128 output tile per block ----
__global__ __launch_bounds__(256) void gconv_kernel(
    const float* __restrict__ atoms,          // [210000][128] fp32
    const float* __restrict__ W,              // [13][k][n] fp32 (fallback path)
    const unsigned short* __restrict__ Wt,    // [13][n][k] bf16 (fast path)
    const float* __restrict__ bvec,           // [13][128] fp32
    const int* __restrict__ adj1, const int* __restrict__ adj2,
    const int* __restrict__ adj3, const int* __restrict__ adj4,
    const int* __restrict__ adj5, const int* __restrict__ adj6,
    const int use_wt,
    float* __restrict__ out)                  // [210000][128] fp32
{
    __shared__ unsigned short sA[TM * LDK];   // 17408 B

    const int tid  = threadIdx.x;
    const int lane = tid & 63;
    const int wave = tid >> 6;
    const int wr   = wave >> 1, wc = wave & 1;   // 2x2 waves over 64x128 tile
    const int deg  = blockIdx.y;
    const int row0_local = blockIdx.x * TM;
    const int valid = min(TM, NPD - row0_local);
    const int row0g = deg * NPD + row0_local;

    floatx4 acc[2][4];
#pragma unroll
    for (int i = 0; i < 2; i++)
#pragma unroll
        for (int j = 0; j < 4; j++) acc[i][j] = (floatx4){0.f, 0.f, 0.f, 0.f};

    const int nb = lane & 15;          // fragment row/col within 16
    const int kq = (lane >> 4) * 8;    // quad k-offset (bf16 elems)

    // MFMA over full K=128 from sA against affine slab wi
    auto run_phase = [&](int wi) {
        const unsigned short* Wtp = Wt + (size_t)wi * NF * NF;
        const float*          Wfp = W  + (size_t)wi * NF * NF;
#pragma unroll
        for (int kk = 0; kk < 4; ++kk) {
            short8 bfr[4];
            if (use_wt) {
#pragma unroll
                for (int nt = 0; nt < 4; ++nt)
                    bfr[nt] = *(const short8*)(Wtp + (size_t)(wc * 64 + nt * 16 + nb) * NF
                                               + kk * 32 + kq);
            } else {
#pragma unroll
                for (int nt = 0; nt < 4; ++nt) {
                    short8 f;
#pragma unroll
                    for (int j = 0; j < 8; ++j)
                        f[j] = (short)f2bf(Wfp[(size_t)(kk * 32 + kq + j) * NF
                                               + (wc * 64 + nt * 16 + nb)]);
                    bfr[nt] = f;
                }
            }
            short8 af[2];
#pragma unroll
            for (int mt = 0; mt < 2; ++mt)
                af[mt] = *(const short8*)(&sA[(wr * 32 + mt * 16 + nb) * LDK + kk * 32 + kq]);
#pragma unroll
            for (int mt = 0; mt < 2; ++mt)
#pragma unroll
                for (int nt = 0; nt < 4; ++nt)
                    acc[mt][nt] = __builtin_amdgcn_mfma_f32_16x16x32_bf16(
                        af[mt], bfr[nt], acc[mt][nt], 0, 0, 0);
        }
    };

    // thread mapping for staging/gather: 4 threads per row, 32 cols each
    const int rS  = tid >> 2;             // 0..63
    const int kcS = (tid & 3) << 5;       // 0, 32, 64, 96
    const int rrS = min(rS, valid - 1);

    // ---- phase 1: self rows (contiguous, coalesced, fp32->bf16) ----
    {
        const float4* p = (const float4*)(atoms + (size_t)(row0g + rrS) * NF + kcS);
        unsigned ww[16];
#pragma unroll
        for (int q = 0; q < 8; q++) {
            float4 v = p[q];
            ww[q * 2 + 0] = (unsigned)f2bf(v.x) | ((unsigned)f2bf(v.y) << 16);
            ww[q * 2 + 1] = (unsigned)f2bf(v.z) | ((unsigned)f2bf(v.w) << 16);
        }
#pragma unroll
        for (int s = 0; s < 4; s++)
            *(uint4*)(&sA[rS * LDK + kcS + s * 8]) = *(uint4*)&ww[s * 4];
    }
    const int wi_self = (deg == 0) ? 12 : (2 * deg - 1);
    __syncthreads();
    run_phase(wi_self);

    // ---- phase 2: gathered neighbor sums ----
    if (deg > 0) {
        __syncthreads();  // all waves done reading sA (phase 1)
        float a32[32];
        const int rg = row0_local + rrS;
        switch (deg) {
            case 1: gather_sum<1>(adj1, atoms, rg, kcS, a32); break;
            case 2: gather_sum<2>(adj2, atoms, rg, kcS, a32); break;
            case 3: gather_sum<3>(adj3, atoms, rg, kcS, a32); break;
            case 4: gather_sum<4>(adj4, atoms, rg, kcS, a32); break;
            case 5: gather_sum<5>(adj5, atoms, rg, kcS, a32); break;
            default: gather_sum<6>(adj6, atoms, rg, kcS, a32); break;
        }
        unsigned ww[16];
#pragma unroll
        for (int i = 0; i < 16; i++)
            ww[i] = (unsigned)f2bf(a32[2 * i]) | ((unsigned)f2bf(a32[2 * i + 1]) << 16);
#pragma unroll
        for (int s = 0; s < 4; s++)
            *(uint4*)(&sA[rS * LDK + kcS + s * 8]) = *(uint4*)&ww[s * 4];
        __syncthreads();
        run_phase(2 * (deg - 1));
    }

    // ---- epilogue: bias + fp32 store ----
    float bias[4];
#pragma unroll
    for (int nt = 0; nt < 4; nt++) {
        int n = wc * 64 + nt * 16 + nb;
        float bv = bvec[wi_self * NF + n];
        if (deg > 0) bv += bvec[(2 * (deg - 1)) * NF + n];
        bias[nt] = bv;
    }
    const int rq = (lane >> 4) << 2;
#pragma unroll
    for (int mt = 0; mt < 2; mt++) {
        int rb = wr * 32 + mt * 16 + rq;
#pragma unroll
        for (int reg = 0; reg < 4; reg++) {
            int r = rb + reg;
            if (r < valid) {
                float* op = out + (size_t)(row0g + r) * NF;
#pragma unroll
                for (int nt = 0; nt < 4; nt++) {
                    int n = wc * 64 + nt * 16 + nb;
                    op[n] = acc[mt][nt][reg] + bias[nt];
                }
            }
        }
    }
}

extern "C" void kernel_launch(void* const* d_in, const int* in_sizes, int n_in,
                              void* d_out, int out_size, void* d_ws, size_t ws_size,
                              hipStream_t stream) {
    const float* atoms = (const float*)d_in[0];
    const float* W     = (const float*)d_in[1];
    const float* b     = (const float*)d_in[2];
    // d_in[3] = deg_slice (static, unused)
    const int* adj1 = (const int*)d_in[4];
    const int* adj2 = (const int*)d_in[5];
    const int* adj3 = (const int*)d_in[6];
    const int* adj4 = (const int*)d_in[7];
    const int* adj5 = (const int*)d_in[8];
    const int* adj6 = (const int*)d_in[9];

    const size_t wt_bytes = (size_t)13 * NF * NF * sizeof(unsigned short);  // 425984
    const int use_wt = (ws_size >= wt_bytes) ? 1 : 0;
    unsigned short* Wt = (unsigned short*)d_ws;

    if (use_wt)
        wt_kernel<<<dim3(4, 4, 13), 256, 0, stream>>>(W, Wt);
    gconv_kernel<<<dim3((NPD + TM - 1) / TM, MAXDEG + 1), 256, 0, stream>>>(
        atoms, W, Wt, b, adj1, adj2, adj3, adj4, adj5, adj6, use_wt,
        (float*)d_out);
}